// Round 7
// baseline (957.268 us; speedup 1.0000x reference)
//
#include <hip/hip_runtime.h>
#include <math.h>

#define M1 100000
#define FF 256
#define UU 256
#define FED 128
#define TT 3
#define EE 131072
#define EPB 32
#define SCAN_B 98   // ceil(100000/1024)

typedef __attribute__((ext_vector_type(8))) short short8;
typedef __attribute__((ext_vector_type(4))) float f32x4;

static __device__ __forceinline__ ushort f2bf(float x) {
    union { float f; uint u; } c; c.f = x;
    const uint u = c.u;
    return (ushort)((u + 0x7FFFu + ((u >> 16) & 1u)) >> 16);  // RTNE
}
static __device__ __forceinline__ float bf2f(ushort h) {
    union { uint u; float f; } c; c.u = ((uint)h) << 16;
    return c.f;
}

// ---- prep: convert + transpose weights to bf16 [n][k] layouts in ws ----
__global__ __launch_bounds__(256) void k_prep(const float* __restrict__ Wg,
                                              const float* __restrict__ Wge,
                                              const float* __restrict__ Wde,
                                              short* __restrict__ WtG,
                                              short* __restrict__ WtGe,
                                              short* __restrict__ WtDe) {
    const int idx = blockIdx.x * 256 + threadIdx.x;  // 262144 total
    if (idx < 65536) {                               // W_gate: [256k][256n] -> [256n][256k]
        const int n = idx >> 8, k = idx & 255;
        WtG[n * 256 + k] = (short)f2bf(Wg[k * 256 + n]);
    } else {
        int j = idx - 65536;                         // 2*98304 for Wge/Wde
        const float* src = Wge;
        short* dst = WtGe;
        if (j >= 98304) { j -= 98304; src = Wde; dst = WtDe; }
        const int t = j >> 15, rem = j & 32767;      // 32768 per type
        const int n = rem >> 7, k = rem & 127;
        dst[t * 32768 + n * 128 + k] = (short)f2bf(src[t * 32768 + k * 256 + n]);
    }
}

// ---- Kernel 1: src_gated = features @ W_gate (bf16 MFMA), output bf16 ----
__global__ __launch_bounds__(256) void k1_srcgate(const float* __restrict__ feats,
                                                  const short* __restrict__ WtG,
                                                  ushort* __restrict__ sg) {
    __shared__ char As[32 * 512];  // 32 rows x 256 bf16, XOR-swizzled
    const int tid = threadIdx.x, lane = tid & 63, wid = tid >> 6;
    const int r0 = blockIdx.x * 32;

    const float* src = feats + (size_t)r0 * FF;
#pragma unroll
    for (int j = 0; j < 4; ++j) {
        const int chunk = j * 256 + tid;             // 1024 chunks of 8 floats
        const int row = chunk >> 5, kc = chunk & 31;
        const float4 f0 = *(const float4*)(src + row * FF + kc * 8);
        const float4 f1 = *(const float4*)(src + row * FF + kc * 8 + 4);
        short8 v;
        v[0]=(short)f2bf(f0.x); v[1]=(short)f2bf(f0.y); v[2]=(short)f2bf(f0.z); v[3]=(short)f2bf(f0.w);
        v[4]=(short)f2bf(f1.x); v[5]=(short)f2bf(f1.y); v[6]=(short)f2bf(f1.z); v[7]=(short)f2bf(f1.w);
        int byte = row * 512 + kc * 16;
        byte ^= (row & 7) << 4;
        *(short8*)(As + byte) = v;
    }
    __syncthreads();

    const int nb = wid * 64;
    f32x4 acc[2][4];
#pragma unroll
    for (int m = 0; m < 2; ++m)
#pragma unroll
        for (int n = 0; n < 4; ++n) acc[m][n] = (f32x4){0.f, 0.f, 0.f, 0.f};

    for (int ks = 0; ks < 8; ++ks) {
        short8 a[2];
#pragma unroll
        for (int m = 0; m < 2; ++m) {
            const int row = m * 16 + (lane & 15);
            int byte = row * 512 + ks * 64 + (lane >> 4) * 16;
            byte ^= (row & 7) << 4;
            a[m] = *(const short8*)(As + byte);
        }
#pragma unroll
        for (int n = 0; n < 4; ++n) {
            const int col = nb + n * 16 + (lane & 15);
            const short8 b = *(const short8*)(WtG + col * 256 + ks * 32 + (lane >> 4) * 8);
#pragma unroll
            for (int m = 0; m < 2; ++m)
                acc[m][n] = __builtin_amdgcn_mfma_f32_16x16x32_bf16(a[m], b, acc[m][n], 0, 0, 0);
        }
    }
#pragma unroll
    for (int m = 0; m < 2; ++m)
#pragma unroll
        for (int n = 0; n < 4; ++n) {
            const int col = nb + n * 16 + (lane & 15);
#pragma unroll
            for (int r = 0; r < 4; ++r) {
                const int row = m * 16 + (lane >> 4) * 4 + r;
                sg[(size_t)(r0 + row) * UU + col] = f2bf(acc[m][n][r]);
            }
        }
}

// ---- sort pipeline: counting sort of edges by destination node, per type ----
__global__ __launch_bounds__(256) void k_hist(const int* __restrict__ eidx,
                                              int* __restrict__ cnt) {
    const int idx = blockIdx.x * 256 + threadIdx.x;   // 393216
    atomicAdd(&cnt[(idx >> 17) * M1 + eidx[idx]], 1);
}

__global__ __launch_bounds__(1024) void k_scan1(int* __restrict__ cnt,
                                                int* __restrict__ part) {
    const int t = blockIdx.x / SCAN_B, b = blockIdx.x % SCAN_B;
    const int i = b * 1024 + threadIdx.x;
    __shared__ int s[1024];
    const int v = (i < M1) ? cnt[t * M1 + i] : 0;
    s[threadIdx.x] = v;
    __syncthreads();
    for (int off = 1; off < 1024; off <<= 1) {
        const int x = (threadIdx.x >= off) ? s[threadIdx.x - off] : 0;
        __syncthreads();
        s[threadIdx.x] += x;
        __syncthreads();
    }
    if (i < M1) cnt[t * M1 + i] = s[threadIdx.x] - v;   // exclusive
    if (threadIdx.x == 1023) part[blockIdx.x] = s[1023];
}

__global__ void k_scan2(int* __restrict__ part) {
    const int t = threadIdx.x;
    if (t < TT) {
        int run = 0;
        for (int b = 0; b < SCAN_B; ++b) {
            const int p = part[t * SCAN_B + b];
            part[t * SCAN_B + b] = run;
            run += p;
        }
    }
}

__global__ __launch_bounds__(1024) void k_scan3(int* __restrict__ cnt,
                                                const int* __restrict__ part) {
    const int t = blockIdx.x / SCAN_B, b = blockIdx.x % SCAN_B;
    const int i = b * 1024 + threadIdx.x;
    if (i < M1) cnt[t * M1 + i] += part[blockIdx.x];
}

__global__ __launch_bounds__(256) void k_scatter(const int* __restrict__ eidx,
                                                 int* __restrict__ cur,
                                                 int* __restrict__ sorted) {
    const int idx = blockIdx.x * 256 + threadIdx.x;   // 393216
    const int t = idx >> 17;
    const int slot = atomicAdd(&cur[t * M1 + eidx[idx]], 1);
    sorted[t * EE + slot] = idx & (EE - 1);
}
// NOTE: after k_scatter, cnt[t*M1+v] == end offset of node v's segment;
// start(v) = (v==0) ? 0 : cnt[t*M1+v-1].

// ---- Phase A: edge GEMMs in SORTED order, msgs written CSR-contiguous ----
__global__ __launch_bounds__(256, 6) void k2_msgs(const int* __restrict__ eidx,
                                                  const float* __restrict__ efeat,
                                                  const short* __restrict__ WtGe,
                                                  const short* __restrict__ WtDe,
                                                  const float* __restrict__ bd,
                                                  const ushort* __restrict__ sg,
                                                  const int* __restrict__ sorted,
                                                  ushort* __restrict__ msgs) {
    __shared__ char As[EPB * 256];        // 32 edges x 128 bf16, XOR-swizzled
    __shared__ ushort sgl[EPB][260];      // gathered sg rows (+4 pad)
    __shared__ int nds[EPB];
    const int tid = threadIdx.x, lane = tid & 63, wid = tid >> 6;
    const int t = blockIdx.y;
    const int e0 = blockIdx.x * EPB;
    const int* sortedT = sorted + t * EE + e0;

    if (tid < EPB) nds[tid] = eidx[t * EE + sortedT[tid]];

    // stage efeat rows gathered by sorted edge id, convert to bf16, swizzle
#pragma unroll
    for (int j = 0; j < 2; ++j) {
        const int chunk = j * 256 + tid;             // 512 chunks of 8 floats
        const int row = chunk >> 4, kc = chunk & 15;
        const int se = sortedT[row];
        const float* src = efeat + ((size_t)t * EE + se) * FED + kc * 8;
        const float4 f0 = *(const float4*)(src);
        const float4 f1 = *(const float4*)(src + 4);
        short8 v;
        v[0]=(short)f2bf(f0.x); v[1]=(short)f2bf(f0.y); v[2]=(short)f2bf(f0.z); v[3]=(short)f2bf(f0.w);
        v[4]=(short)f2bf(f1.x); v[5]=(short)f2bf(f1.y); v[6]=(short)f2bf(f1.z); v[7]=(short)f2bf(f1.w);
        int byte = row * 256 + kc * 16;
        byte ^= (row & 7) << 4;
        *(short8*)(As + byte) = v;
    }
    __syncthreads();

    // coalesced pre-gather of the 32 needed sg rows (nodes clustered by sort)
#pragma unroll
    for (int j = 0; j < 16; ++j) {
        const int item = j * 256 + tid;              // 4096 uint items
        const int row = item >> 7, c2 = item & 127;
        const uint v = *(const uint*)(sg + (size_t)nds[row] * UU + c2 * 2);
        *(uint*)&sgl[row][c2 * 2] = v;
    }

    const short* Bg = WtGe + t * 32768;  // [256n][128k]
    const short* Bd = WtDe + t * 32768;
    const int nb = wid * 64;

    f32x4 accg[2][4], accv[2][4];
#pragma unroll
    for (int m = 0; m < 2; ++m)
#pragma unroll
        for (int n = 0; n < 4; ++n) {
            accg[m][n] = (f32x4){0.f, 0.f, 0.f, 0.f};
            accv[m][n] = (f32x4){0.f, 0.f, 0.f, 0.f};
        }

#pragma unroll
    for (int ks = 0; ks < 4; ++ks) {
        short8 a[2];
#pragma unroll
        for (int m = 0; m < 2; ++m) {
            const int row = m * 16 + (lane & 15);
            int byte = row * 256 + ks * 64 + (lane >> 4) * 16;
            byte ^= (row & 7) << 4;
            a[m] = *(const short8*)(As + byte);
        }
#pragma unroll
        for (int n = 0; n < 4; ++n) {
            const int col = nb + n * 16 + (lane & 15);
            const int koff = ks * 32 + (lane >> 4) * 8;
            const short8 bg = *(const short8*)(Bg + col * 128 + koff);
            const short8 bv = *(const short8*)(Bd + col * 128 + koff);
#pragma unroll
            for (int m = 0; m < 2; ++m) {
                accg[m][n] = __builtin_amdgcn_mfma_f32_16x16x32_bf16(a[m], bg, accg[m][n], 0, 0, 0);
                accv[m][n] = __builtin_amdgcn_mfma_f32_16x16x32_bf16(a[m], bv, accv[m][n], 0, 0, 0);
            }
        }
    }
    __syncthreads();  // sgl ready

    float bias[4];
#pragma unroll
    for (int n = 0; n < 4; ++n) bias[n] = bd[t * UU + nb + n * 16 + (lane & 15)];

#pragma unroll
    for (int m = 0; m < 2; ++m) {
        const int ebase = m * 16 + (lane >> 4) * 4;
#pragma unroll
        for (int n = 0; n < 4; ++n) {
            const int col = nb + n * 16 + (lane & 15);
#pragma unroll
            for (int r = 0; r < 4; ++r) {
                const float sgv = bf2f(sgl[ebase + r][col]);
                const float g = 1.f / (1.f + __expf(-(sgv + accg[m][n][r])));
                const float msg = (accv[m][n][r] + bias[n]) * g;
                // sorted position -> CSR-contiguous message matrix
                msgs[((size_t)t * EE + e0 + ebase + r) * UU + col] = f2bf(msg);
            }
        }
    }
}

// ---- Phase B: per-node contiguous segment reduce, plain stores ----
__global__ __launch_bounds__(256, 8) void k3_reduce(const int* __restrict__ cnt,
                                                    const ushort* __restrict__ msgs,
                                                    float* __restrict__ out) {
    const int tid = threadIdx.x, lane = tid & 63, w = tid >> 6;
    const int v = blockIdx.x * 4 + w;   // node id, 4 waves/block; grid=25000
    float a0 = 0.f, a1 = 0.f, a2 = 0.f, a3 = 0.f;
#pragma unroll
    for (int t = 0; t < TT; ++t) {
        const int end   = cnt[t * M1 + v];
        const int start = (v == 0) ? 0 : cnt[t * M1 + v - 1];
        for (int e = start; e < end; ++e) {
            const uint2 d = *(const uint2*)(msgs + ((size_t)t * EE + e) * UU + lane * 4);
            a0 += bf2f((ushort)(d.x & 0xffff));
            a1 += bf2f((ushort)(d.x >> 16));
            a2 += bf2f((ushort)(d.y & 0xffff));
            a3 += bf2f((ushort)(d.y >> 16));
        }
    }
    float4 o; o.x = a0; o.y = a1; o.z = a2; o.w = a3;
    *(float4*)(out + (size_t)v * UU + lane * 4) = o;
}

// ---- Fallback (small ws): round-5 sorted + atomic kernel ----
__global__ __launch_bounds__(256, 4) void k2_edges(const int* __restrict__ eidx,
                                                   const float* __restrict__ efeat,
                                                   const short* __restrict__ WtGe,
                                                   const short* __restrict__ WtDe,
                                                   const float* __restrict__ bd,
                                                   const ushort* __restrict__ sg,
                                                   const int* __restrict__ sorted,
                                                   float* __restrict__ out) {
    __shared__ char As[EPB * 256];
    __shared__ ushort sgl[EPB][260];
    __shared__ int nds[EPB];
    const int tid = threadIdx.x, lane = tid & 63, wid = tid >> 6;
    const int t = blockIdx.y;
    const int e0 = blockIdx.x * EPB;
    const int* sortedT = sorted + t * EE + e0;
    const int* eidxT   = eidx + t * EE;

    if (tid < EPB) nds[tid] = eidxT[sortedT[tid]];
#pragma unroll
    for (int j = 0; j < 2; ++j) {
        const int chunk = j * 256 + tid;
        const int row = chunk >> 4, kc = chunk & 15;
        const int se = sortedT[row];
        const float* src = efeat + ((size_t)t * EE + se) * FED + kc * 8;
        const float4 f0 = *(const float4*)(src);
        const float4 f1 = *(const float4*)(src + 4);
        short8 v;
        v[0]=(short)f2bf(f0.x); v[1]=(short)f2bf(f0.y); v[2]=(short)f2bf(f0.z); v[3]=(short)f2bf(f0.w);
        v[4]=(short)f2bf(f1.x); v[5]=(short)f2bf(f1.y); v[6]=(short)f2bf(f1.z); v[7]=(short)f2bf(f1.w);
        int byte = row * 256 + kc * 16;
        byte ^= (row & 7) << 4;
        *(short8*)(As + byte) = v;
    }
    __syncthreads();
#pragma unroll
    for (int j = 0; j < 16; ++j) {
        const int item = j * 256 + tid;
        const int row = item >> 7, c2 = item & 127;
        const uint v = *(const uint*)(sg + (size_t)nds[row] * UU + c2 * 2);
        *(uint*)&sgl[row][c2 * 2] = v;
    }
    const short* Bg = WtGe + t * 32768;
    const short* Bd = WtDe + t * 32768;
    const int nb = wid * 64;
    f32x4 accg[2][4], accv[2][4];
#pragma unroll
    for (int m = 0; m < 2; ++m)
#pragma unroll
        for (int n = 0; n < 4; ++n) {
            accg[m][n] = (f32x4){0.f, 0.f, 0.f, 0.f};
            accv[m][n] = (f32x4){0.f, 0.f, 0.f, 0.f};
        }
#pragma unroll
    for (int ks = 0; ks < 4; ++ks) {
        short8 a[2];
#pragma unroll
        for (int m = 0; m < 2; ++m) {
            const int row = m * 16 + (lane & 15);
            int byte = row * 256 + ks * 64 + (lane >> 4) * 16;
            byte ^= (row & 7) << 4;
            a[m] = *(const short8*)(As + byte);
        }
#pragma unroll
        for (int n = 0; n < 4; ++n) {
            const int col = nb + n * 16 + (lane & 15);
            const int koff = ks * 32 + (lane >> 4) * 8;
            const short8 bg = *(const short8*)(Bg + col * 128 + koff);
            const short8 bv = *(const short8*)(Bd + col * 128 + koff);
#pragma unroll
            for (int m = 0; m < 2; ++m) {
                accg[m][n] = __builtin_amdgcn_mfma_f32_16x16x32_bf16(a[m], bg, accg[m][n], 0, 0, 0);
                accv[m][n] = __builtin_amdgcn_mfma_f32_16x16x32_bf16(a[m], bv, accv[m][n], 0, 0, 0);
            }
        }
    }
    __syncthreads();
    float bias[4];
#pragma unroll
    for (int n = 0; n < 4; ++n) bias[n] = bd[t * UU + nb + n * 16 + (lane & 15)];
#pragma unroll
    for (int m = 0; m < 2; ++m) {
        const int ebase = m * 16 + (lane >> 4) * 4;
        int node[4];
#pragma unroll
        for (int r = 0; r < 4; ++r) node[r] = nds[ebase + r];
#pragma unroll
        for (int n = 0; n < 4; ++n) {
            const int col = nb + n * 16 + (lane & 15);
            float carry = 0.f;
#pragma unroll
            for (int r = 0; r < 4; ++r) {
                const float sgv = bf2f(sgl[ebase + r][col]);
                const float g = 1.f / (1.f + __expf(-(sgv + accg[m][n][r])));
                carry += (accv[m][n][r] + bias[n]) * g;
                if (r == 3 || node[r + 1] != node[r]) {
                    atomicAdd(&out[(size_t)node[r] * UU + col], carry);
                    carry = 0.f;
                }
            }
        }
    }
}

extern "C" void kernel_launch(void* const* d_in, const int* in_sizes, int n_in,
                              void* d_out, int out_size, void* d_ws, size_t ws_size,
                              hipStream_t stream) {
    const float* feats = (const float*)d_in[0];
    const int*   eidx  = (const int*)d_in[1];
    const float* efeat = (const float*)d_in[2];
    const float* Wg    = (const float*)d_in[3];
    const float* Wge   = (const float*)d_in[4];
    const float* Wde   = (const float*)d_in[5];
    const float* bd    = (const float*)d_in[6];
    float* out = (float*)d_out;

    char* ws = (char*)d_ws;
    size_t off = 0;
    auto alloc = [&](size_t bytes) { char* p = ws + off; off = (off + bytes + 511) & ~(size_t)511; return p; };
    ushort* sg   = (ushort*)alloc((size_t)M1 * UU * 2);          // 51.2 MB
    short* WtG   = (short*)alloc(256 * 256 * 2);
    short* WtGe  = (short*)alloc((size_t)TT * FED * UU * 2);
    short* WtDe  = (short*)alloc((size_t)TT * FED * UU * 2);
    int* cnt     = (int*)alloc((size_t)TT * M1 * 4);             // 1.2 MB
    int* part    = (int*)alloc(4096);
    int* sorted  = (int*)alloc((size_t)TT * EE * 4);             // 1.57 MB
    const size_t small_needed = off;
    ushort* msgs = (ushort*)alloc((size_t)TT * EE * UU * 2);     // 201.3 MB
    const size_t big_needed = off;

    hipMemsetAsync(cnt, 0, (size_t)TT * M1 * 4, stream);
    k_prep<<<262144 / 256, 256, 0, stream>>>(Wg, Wge, Wde, WtG, WtGe, WtDe);
    k1_srcgate<<<M1 / 32, 256, 0, stream>>>(feats, WtG, sg);

    k_hist<<<(TT * EE) / 256, 256, 0, stream>>>(eidx, cnt);
    k_scan1<<<TT * SCAN_B, 1024, 0, stream>>>(cnt, part);
    k_scan2<<<1, 64, 0, stream>>>(part);
    k_scan3<<<TT * SCAN_B, 1024, 0, stream>>>(cnt, part);
    k_scatter<<<(TT * EE) / 256, 256, 0, stream>>>(eidx, cnt, sorted);

    if (ws_size >= big_needed) {
        k2_msgs<<<dim3(EE / EPB, TT), 256, 0, stream>>>(eidx, efeat, WtGe, WtDe, bd,
                                                        (const ushort*)sg, sorted, msgs);
        k3_reduce<<<M1 / 4, 256, 0, stream>>>(cnt, (const ushort*)msgs, out);
    } else if (ws_size >= small_needed) {
        hipMemsetAsync(d_out, 0, (size_t)out_size * sizeof(float), stream);
        k2_edges<<<dim3(EE / EPB, TT), 256, 0, stream>>>(eidx, efeat, WtGe, WtDe, bd,
                                                         (const ushort*)sg, sorted, out);
    }
}

// Round 8
// 519.976 us; speedup vs baseline: 1.8410x; 1.8410x over previous
//
#include <hip/hip_runtime.h>
#include <math.h>

#define M1 100000
#define FF 256
#define UU 256
#define FED 128
#define TT 3
#define EE 131072
#define EPB 32
#define SCAN_B 98   // ceil(100000/1024)

typedef __attribute__((ext_vector_type(8))) short short8;
typedef __attribute__((ext_vector_type(4))) float f32x4;

static __device__ __forceinline__ ushort f2bf(float x) {
    union { float f; uint u; } c; c.f = x;
    const uint u = c.u;
    return (ushort)((u + 0x7FFFu + ((u >> 16) & 1u)) >> 16);  // RTNE
}
static __device__ __forceinline__ float bf2f(ushort h) {
    union { uint u; float f; } c; c.u = ((uint)h) << 16;
    return c.f;
}

// ---- prep: convert + transpose weights to bf16 [n][k] layouts in ws ----
__global__ __launch_bounds__(256) void k_prep(const float* __restrict__ Wg,
                                              const float* __restrict__ Wge,
                                              const float* __restrict__ Wde,
                                              short* __restrict__ WtG,
                                              short* __restrict__ WtGe,
                                              short* __restrict__ WtDe) {
    const int idx = blockIdx.x * 256 + threadIdx.x;  // 262144 total
    if (idx < 65536) {                               // W_gate: [256k][256n] -> [256n][256k]
        const int n = idx >> 8, k = idx & 255;
        WtG[n * 256 + k] = (short)f2bf(Wg[k * 256 + n]);
    } else {
        int j = idx - 65536;                         // 2*98304 for Wge/Wde
        const float* src = Wge;
        short* dst = WtGe;
        if (j >= 98304) { j -= 98304; src = Wde; dst = WtDe; }
        const int t = j >> 15, rem = j & 32767;      // 32768 per type
        const int n = rem >> 7, k = rem & 127;
        dst[t * 32768 + n * 128 + k] = (short)f2bf(src[t * 32768 + k * 256 + n]);
    }
}

// ---- Kernel 1: src_gated = features @ W_gate (bf16 MFMA), output bf16 ----
__global__ __launch_bounds__(256) void k1_srcgate(const float* __restrict__ feats,
                                                  const short* __restrict__ WtG,
                                                  ushort* __restrict__ sg) {
    __shared__ char As[32 * 512];  // 32 rows x 256 bf16, XOR-swizzled
    const int tid = threadIdx.x, lane = tid & 63, wid = tid >> 6;
    const int r0 = blockIdx.x * 32;

    const float* src = feats + (size_t)r0 * FF;
#pragma unroll
    for (int j = 0; j < 4; ++j) {
        const int chunk = j * 256 + tid;             // 1024 chunks of 8 floats
        const int row = chunk >> 5, kc = chunk & 31;
        const float4 f0 = *(const float4*)(src + row * FF + kc * 8);
        const float4 f1 = *(const float4*)(src + row * FF + kc * 8 + 4);
        short8 v;
        v[0]=(short)f2bf(f0.x); v[1]=(short)f2bf(f0.y); v[2]=(short)f2bf(f0.z); v[3]=(short)f2bf(f0.w);
        v[4]=(short)f2bf(f1.x); v[5]=(short)f2bf(f1.y); v[6]=(short)f2bf(f1.z); v[7]=(short)f2bf(f1.w);
        int byte = row * 512 + kc * 16;
        byte ^= (row & 7) << 4;
        *(short8*)(As + byte) = v;
    }
    __syncthreads();

    const int nb = wid * 64;
    f32x4 acc[2][4];
#pragma unroll
    for (int m = 0; m < 2; ++m)
#pragma unroll
        for (int n = 0; n < 4; ++n) acc[m][n] = (f32x4){0.f, 0.f, 0.f, 0.f};

    for (int ks = 0; ks < 8; ++ks) {
        short8 a[2];
#pragma unroll
        for (int m = 0; m < 2; ++m) {
            const int row = m * 16 + (lane & 15);
            int byte = row * 512 + ks * 64 + (lane >> 4) * 16;
            byte ^= (row & 7) << 4;
            a[m] = *(const short8*)(As + byte);
        }
#pragma unroll
        for (int n = 0; n < 4; ++n) {
            const int col = nb + n * 16 + (lane & 15);
            const short8 b = *(const short8*)(WtG + col * 256 + ks * 32 + (lane >> 4) * 8);
#pragma unroll
            for (int m = 0; m < 2; ++m)
                acc[m][n] = __builtin_amdgcn_mfma_f32_16x16x32_bf16(a[m], b, acc[m][n], 0, 0, 0);
        }
    }
#pragma unroll
    for (int m = 0; m < 2; ++m)
#pragma unroll
        for (int n = 0; n < 4; ++n) {
            const int col = nb + n * 16 + (lane & 15);
#pragma unroll
            for (int r = 0; r < 4; ++r) {
                const int row = m * 16 + (lane >> 4) * 4 + r;
                sg[(size_t)(r0 + row) * UU + col] = f2bf(acc[m][n][r]);
            }
        }
}

// ---- sort pipeline: counting sort of edges by destination node, per type ----
__global__ __launch_bounds__(256) void k_hist(const int* __restrict__ eidx,
                                              int* __restrict__ cnt) {
    const int idx = blockIdx.x * 256 + threadIdx.x;   // 393216
    atomicAdd(&cnt[(idx >> 17) * M1 + eidx[idx]], 1);
}

__global__ __launch_bounds__(1024) void k_scan1(int* __restrict__ cnt,
                                                int* __restrict__ part) {
    const int t = blockIdx.x / SCAN_B, b = blockIdx.x % SCAN_B;
    const int i = b * 1024 + threadIdx.x;
    __shared__ int s[1024];
    const int v = (i < M1) ? cnt[t * M1 + i] : 0;
    s[threadIdx.x] = v;
    __syncthreads();
    for (int off = 1; off < 1024; off <<= 1) {
        const int x = (threadIdx.x >= off) ? s[threadIdx.x - off] : 0;
        __syncthreads();
        s[threadIdx.x] += x;
        __syncthreads();
    }
    if (i < M1) cnt[t * M1 + i] = s[threadIdx.x] - v;   // exclusive
    if (threadIdx.x == 1023) part[blockIdx.x] = s[1023];
}

__global__ void k_scan2(int* __restrict__ part) {
    const int t = threadIdx.x;
    if (t < TT) {
        int run = 0;
        for (int b = 0; b < SCAN_B; ++b) {
            const int p = part[t * SCAN_B + b];
            part[t * SCAN_B + b] = run;
            run += p;
        }
    }
}

__global__ __launch_bounds__(1024) void k_scan3(int* __restrict__ cnt,
                                                const int* __restrict__ part) {
    const int t = blockIdx.x / SCAN_B, b = blockIdx.x % SCAN_B;
    const int i = b * 1024 + threadIdx.x;
    if (i < M1) cnt[t * M1 + i] += part[blockIdx.x];
}

__global__ __launch_bounds__(256) void k_scatter(const int* __restrict__ eidx,
                                                 int* __restrict__ cur,
                                                 int* __restrict__ sorted) {
    const int idx = blockIdx.x * 256 + threadIdx.x;   // 393216
    const int t = idx >> 17;
    const int slot = atomicAdd(&cur[t * M1 + eidx[idx]], 1);
    sorted[t * EE + slot] = idx & (EE - 1);
}
// NOTE: after k_scatter, cnt[t*M1+v] == end offset of node v's segment;
// start(v) = (v==0) ? 0 : cnt[t*M1+v-1].

// ---- Phase A: edge GEMMs in SORTED order, msgs written CSR-contiguous ----
// __launch_bounds__(256,4): VGPR=64, no spill (round-7's (256,6) spilled
// the accumulators to scratch -> 2.6 GB of HBM traffic).
__global__ __launch_bounds__(256, 4) void k2_msgs(const int* __restrict__ eidx,
                                                  const float* __restrict__ efeat,
                                                  const short* __restrict__ WtGe,
                                                  const short* __restrict__ WtDe,
                                                  const float* __restrict__ bd,
                                                  const ushort* __restrict__ sg,
                                                  const int* __restrict__ sorted,
                                                  ushort* __restrict__ msgs) {
    __shared__ char As[EPB * 256];        // 32 edges x 128 bf16, XOR-swizzled
    __shared__ ushort sgl[EPB][260];      // gathered sg rows (+4 pad)
    __shared__ int nds[EPB];
    const int tid = threadIdx.x, lane = tid & 63, wid = tid >> 6;
    const int t = blockIdx.y;
    const int e0 = blockIdx.x * EPB;
    const int* sortedT = sorted + t * EE + e0;

    if (tid < EPB) nds[tid] = eidx[t * EE + sortedT[tid]];

    // stage efeat rows gathered by sorted edge id, convert to bf16, swizzle
#pragma unroll
    for (int j = 0; j < 2; ++j) {
        const int chunk = j * 256 + tid;             // 512 chunks of 8 floats
        const int row = chunk >> 4, kc = chunk & 15;
        const int se = sortedT[row];
        const float* src = efeat + ((size_t)t * EE + se) * FED + kc * 8;
        const float4 f0 = *(const float4*)(src);
        const float4 f1 = *(const float4*)(src + 4);
        short8 v;
        v[0]=(short)f2bf(f0.x); v[1]=(short)f2bf(f0.y); v[2]=(short)f2bf(f0.z); v[3]=(short)f2bf(f0.w);
        v[4]=(short)f2bf(f1.x); v[5]=(short)f2bf(f1.y); v[6]=(short)f2bf(f1.z); v[7]=(short)f2bf(f1.w);
        int byte = row * 256 + kc * 16;
        byte ^= (row & 7) << 4;
        *(short8*)(As + byte) = v;
    }
    __syncthreads();

    // coalesced pre-gather of the 32 needed sg rows (nodes clustered by sort)
#pragma unroll
    for (int j = 0; j < 16; ++j) {
        const int item = j * 256 + tid;              // 4096 uint items
        const int row = item >> 7, c2 = item & 127;
        const uint v = *(const uint*)(sg + (size_t)nds[row] * UU + c2 * 2);
        *(uint*)&sgl[row][c2 * 2] = v;
    }

    const short* Bg = WtGe + t * 32768;  // [256n][128k]
    const short* Bd = WtDe + t * 32768;
    const int nb = wid * 64;

    f32x4 accg[2][4], accv[2][4];
#pragma unroll
    for (int m = 0; m < 2; ++m)
#pragma unroll
        for (int n = 0; n < 4; ++n) {
            accg[m][n] = (f32x4){0.f, 0.f, 0.f, 0.f};
            accv[m][n] = (f32x4){0.f, 0.f, 0.f, 0.f};
        }

#pragma unroll
    for (int ks = 0; ks < 4; ++ks) {
        short8 a[2];
#pragma unroll
        for (int m = 0; m < 2; ++m) {
            const int row = m * 16 + (lane & 15);
            int byte = row * 256 + ks * 64 + (lane >> 4) * 16;
            byte ^= (row & 7) << 4;
            a[m] = *(const short8*)(As + byte);
        }
#pragma unroll
        for (int n = 0; n < 4; ++n) {
            const int col = nb + n * 16 + (lane & 15);
            const int koff = ks * 32 + (lane >> 4) * 8;
            const short8 bg = *(const short8*)(Bg + col * 128 + koff);
            const short8 bv = *(const short8*)(Bd + col * 128 + koff);
#pragma unroll
            for (int m = 0; m < 2; ++m) {
                accg[m][n] = __builtin_amdgcn_mfma_f32_16x16x32_bf16(a[m], bg, accg[m][n], 0, 0, 0);
                accv[m][n] = __builtin_amdgcn_mfma_f32_16x16x32_bf16(a[m], bv, accv[m][n], 0, 0, 0);
            }
        }
    }
    __syncthreads();  // sgl ready

    float bias[4];
#pragma unroll
    for (int n = 0; n < 4; ++n) bias[n] = bd[t * UU + nb + n * 16 + (lane & 15)];

#pragma unroll
    for (int m = 0; m < 2; ++m) {
        const int ebase = m * 16 + (lane >> 4) * 4;
#pragma unroll
        for (int n = 0; n < 4; ++n) {
            const int col = nb + n * 16 + (lane & 15);
#pragma unroll
            for (int r = 0; r < 4; ++r) {
                const float sgv = bf2f(sgl[ebase + r][col]);
                const float g = 1.f / (1.f + __expf(-(sgv + accg[m][n][r])));
                const float msg = (accv[m][n][r] + bias[n]) * g;
                // sorted position -> CSR-contiguous message matrix
                msgs[((size_t)t * EE + e0 + ebase + r) * UU + col] = f2bf(msg);
            }
        }
    }
}

// ---- Phase B: per-node contiguous segment reduce, plain stores ----
__global__ __launch_bounds__(256, 8) void k3_reduce(const int* __restrict__ cnt,
                                                    const ushort* __restrict__ msgs,
                                                    float* __restrict__ out) {
    const int tid = threadIdx.x, lane = tid & 63, w = tid >> 6;
    const int v = blockIdx.x * 4 + w;   // node id, 4 waves/block; grid=25000
    float a0 = 0.f, a1 = 0.f, a2 = 0.f, a3 = 0.f;
#pragma unroll
    for (int t = 0; t < TT; ++t) {
        const int end   = cnt[t * M1 + v];
        const int start = (v == 0) ? 0 : cnt[t * M1 + v - 1];
        for (int e = start; e < end; ++e) {
            const uint2 d = *(const uint2*)(msgs + ((size_t)t * EE + e) * UU + lane * 4);
            a0 += bf2f((ushort)(d.x & 0xffff));
            a1 += bf2f((ushort)(d.x >> 16));
            a2 += bf2f((ushort)(d.y & 0xffff));
            a3 += bf2f((ushort)(d.y >> 16));
        }
    }
    float4 o; o.x = a0; o.y = a1; o.z = a2; o.w = a3;
    *(float4*)(out + (size_t)v * UU + lane * 4) = o;
}

// ---- Fallback (small ws): round-5 sorted + atomic kernel ----
__global__ __launch_bounds__(256, 4) void k2_edges(const int* __restrict__ eidx,
                                                   const float* __restrict__ efeat,
                                                   const short* __restrict__ WtGe,
                                                   const short* __restrict__ WtDe,
                                                   const float* __restrict__ bd,
                                                   const ushort* __restrict__ sg,
                                                   const int* __restrict__ sorted,
                                                   float* __restrict__ out) {
    __shared__ char As[EPB * 256];
    __shared__ ushort sgl[EPB][260];
    __shared__ int nds[EPB];
    const int tid = threadIdx.x, lane = tid & 63, wid = tid >> 6;
    const int t = blockIdx.y;
    const int e0 = blockIdx.x * EPB;
    const int* sortedT = sorted + t * EE + e0;
    const int* eidxT   = eidx + t * EE;

    if (tid < EPB) nds[tid] = eidxT[sortedT[tid]];
#pragma unroll
    for (int j = 0; j < 2; ++j) {
        const int chunk = j * 256 + tid;
        const int row = chunk >> 4, kc = chunk & 15;
        const int se = sortedT[row];
        const float* src = efeat + ((size_t)t * EE + se) * FED + kc * 8;
        const float4 f0 = *(const float4*)(src);
        const float4 f1 = *(const float4*)(src + 4);
        short8 v;
        v[0]=(short)f2bf(f0.x); v[1]=(short)f2bf(f0.y); v[2]=(short)f2bf(f0.z); v[3]=(short)f2bf(f0.w);
        v[4]=(short)f2bf(f1.x); v[5]=(short)f2bf(f1.y); v[6]=(short)f2bf(f1.z); v[7]=(short)f2bf(f1.w);
        int byte = row * 256 + kc * 16;
        byte ^= (row & 7) << 4;
        *(short8*)(As + byte) = v;
    }
    __syncthreads();
#pragma unroll
    for (int j = 0; j < 16; ++j) {
        const int item = j * 256 + tid;
        const int row = item >> 7, c2 = item & 127;
        const uint v = *(const uint*)(sg + (size_t)nds[row] * UU + c2 * 2);
        *(uint*)&sgl[row][c2 * 2] = v;
    }
    const short* Bg = WtGe + t * 32768;
    const short* Bd = WtDe + t * 32768;
    const int nb = wid * 64;
    f32x4 accg[2][4], accv[2][4];
#pragma unroll
    for (int m = 0; m < 2; ++m)
#pragma unroll
        for (int n = 0; n < 4; ++n) {
            accg[m][n] = (f32x4){0.f, 0.f, 0.f, 0.f};
            accv[m][n] = (f32x4){0.f, 0.f, 0.f, 0.f};
        }
#pragma unroll
    for (int ks = 0; ks < 4; ++ks) {
        short8 a[2];
#pragma unroll
        for (int m = 0; m < 2; ++m) {
            const int row = m * 16 + (lane & 15);
            int byte = row * 256 + ks * 64 + (lane >> 4) * 16;
            byte ^= (row & 7) << 4;
            a[m] = *(const short8*)(As + byte);
        }
#pragma unroll
        for (int n = 0; n < 4; ++n) {
            const int col = nb + n * 16 + (lane & 15);
            const int koff = ks * 32 + (lane >> 4) * 8;
            const short8 bg = *(const short8*)(Bg + col * 128 + koff);
            const short8 bv = *(const short8*)(Bd + col * 128 + koff);
#pragma unroll
            for (int m = 0; m < 2; ++m) {
                accg[m][n] = __builtin_amdgcn_mfma_f32_16x16x32_bf16(a[m], bg, accg[m][n], 0, 0, 0);
                accv[m][n] = __builtin_amdgcn_mfma_f32_16x16x32_bf16(a[m], bv, accv[m][n], 0, 0, 0);
            }
        }
    }
    __syncthreads();
    float bias[4];
#pragma unroll
    for (int n = 0; n < 4; ++n) bias[n] = bd[t * UU + nb + n * 16 + (lane & 15)];
#pragma unroll
    for (int m = 0; m < 2; ++m) {
        const int ebase = m * 16 + (lane >> 4) * 4;
        int node[4];
#pragma unroll
        for (int r = 0; r < 4; ++r) node[r] = nds[ebase + r];
#pragma unroll
        for (int n = 0; n < 4; ++n) {
            const int col = nb + n * 16 + (lane & 15);
            float carry = 0.f;
#pragma unroll
            for (int r = 0; r < 4; ++r) {
                const float sgv = bf2f(sgl[ebase + r][col]);
                const float g = 1.f / (1.f + __expf(-(sgv + accg[m][n][r])));
                carry += (accv[m][n][r] + bias[n]) * g;
                if (r == 3 || node[r + 1] != node[r]) {
                    atomicAdd(&out[(size_t)node[r] * UU + col], carry);
                    carry = 0.f;
                }
            }
        }
    }
}

extern "C" void kernel_launch(void* const* d_in, const int* in_sizes, int n_in,
                              void* d_out, int out_size, void* d_ws, size_t ws_size,
                              hipStream_t stream) {
    const float* feats = (const float*)d_in[0];
    const int*   eidx  = (const int*)d_in[1];
    const float* efeat = (const float*)d_in[2];
    const float* Wg    = (const float*)d_in[3];
    const float* Wge   = (const float*)d_in[4];
    const float* Wde   = (const float*)d_in[5];
    const float* bd    = (const float*)d_in[6];
    float* out = (float*)d_out;

    char* ws = (char*)d_ws;
    size_t off = 0;
    auto alloc = [&](size_t bytes) { char* p = ws + off; off = (off + bytes + 511) & ~(size_t)511; return p; };
    ushort* sg   = (ushort*)alloc((size_t)M1 * UU * 2);          // 51.2 MB
    short* WtG   = (short*)alloc(256 * 256 * 2);
    short* WtGe  = (short*)alloc((size_t)TT * FED * UU * 2);
    short* WtDe  = (short*)alloc((size_t)TT * FED * UU * 2);
    int* cnt     = (int*)alloc((size_t)TT * M1 * 4);             // 1.2 MB
    int* part    = (int*)alloc(4096);
    int* sorted  = (int*)alloc((size_t)TT * EE * 4);             // 1.57 MB
    const size_t small_needed = off;
    ushort* msgs = (ushort*)alloc((size_t)TT * EE * UU * 2);     // 201.3 MB
    const size_t big_needed = off;

    hipMemsetAsync(cnt, 0, (size_t)TT * M1 * 4, stream);
    k_prep<<<262144 / 256, 256, 0, stream>>>(Wg, Wge, Wde, WtG, WtGe, WtDe);
    k1_srcgate<<<M1 / 32, 256, 0, stream>>>(feats, WtG, sg);

    k_hist<<<(TT * EE) / 256, 256, 0, stream>>>(eidx, cnt);
    k_scan1<<<TT * SCAN_B, 1024, 0, stream>>>(cnt, part);
    k_scan2<<<1, 64, 0, stream>>>(part);
    k_scan3<<<TT * SCAN_B, 1024, 0, stream>>>(cnt, part);
    k_scatter<<<(TT * EE) / 256, 256, 0, stream>>>(eidx, cnt, sorted);

    if (ws_size >= big_needed) {
        k2_msgs<<<dim3(EE / EPB, TT), 256, 0, stream>>>(eidx, efeat, WtGe, WtDe, bd,
                                                        (const ushort*)sg, sorted, msgs);
        k3_reduce<<<M1 / 4, 256, 0, stream>>>(cnt, (const ushort*)msgs, out);
    } else if (ws_size >= small_needed) {
        hipMemsetAsync(d_out, 0, (size_t)out_size * sizeof(float), stream);
        k2_edges<<<dim3(EE / EPB, TT), 256, 0, stream>>>(eidx, efeat, WtGe, WtDe, bd,
                                                         (const ushort*)sg, sorted, out);
    }
}

// Round 9
// 463.099 us; speedup vs baseline: 2.0671x; 1.1228x over previous
//
#include <hip/hip_runtime.h>
#include <math.h>

#define M1 100000
#define FF 256
#define UU 256
#define FED 128
#define TT 3
#define EE 131072
#define EPB 32
#define SCAN_B 98   // ceil(100000/1024)

typedef __attribute__((ext_vector_type(8))) short short8;
typedef __attribute__((ext_vector_type(4))) float f32x4;

static __device__ __forceinline__ ushort f2bf(float x) {
    union { float f; uint u; } c; c.f = x;
    const uint u = c.u;
    return (ushort)((u + 0x7FFFu + ((u >> 16) & 1u)) >> 16);  // RTNE
}
static __device__ __forceinline__ float bf2f(ushort h) {
    union { uint u; float f; } c; c.u = ((uint)h) << 16;
    return c.f;
}

// ---- prep: convert + transpose weights to bf16 [n][k] layouts in ws ----
__global__ __launch_bounds__(256) void k_prep(const float* __restrict__ Wg,
                                              const float* __restrict__ Wge,
                                              const float* __restrict__ Wde,
                                              short* __restrict__ WtG,
                                              short* __restrict__ WtGe,
                                              short* __restrict__ WtDe) {
    const int idx = blockIdx.x * 256 + threadIdx.x;  // 262144 total
    if (idx < 65536) {                               // W_gate: [256k][256n] -> [256n][256k]
        const int n = idx >> 8, k = idx & 255;
        WtG[n * 256 + k] = (short)f2bf(Wg[k * 256 + n]);
    } else {
        int j = idx - 65536;                         // 2*98304 for Wge/Wde
        const float* src = Wge;
        short* dst = WtGe;
        if (j >= 98304) { j -= 98304; src = Wde; dst = WtDe; }
        const int t = j >> 15, rem = j & 32767;      // 32768 per type
        const int n = rem >> 7, k = rem & 127;
        dst[t * 32768 + n * 128 + k] = (short)f2bf(src[t * 32768 + k * 256 + n]);
    }
}

// ---- Kernel 1: src_gated = features @ W_gate (bf16 MFMA), output bf16 ----
__global__ __launch_bounds__(256) void k1_srcgate(const float* __restrict__ feats,
                                                  const short* __restrict__ WtG,
                                                  ushort* __restrict__ sg) {
    __shared__ char As[32 * 512];  // 32 rows x 256 bf16, XOR-swizzled
    const int tid = threadIdx.x, lane = tid & 63, wid = tid >> 6;
    const int r0 = blockIdx.x * 32;

    const float* src = feats + (size_t)r0 * FF;
#pragma unroll
    for (int j = 0; j < 4; ++j) {
        const int chunk = j * 256 + tid;             // 1024 chunks of 8 floats
        const int row = chunk >> 5, kc = chunk & 31;
        const float4 f0 = *(const float4*)(src + row * FF + kc * 8);
        const float4 f1 = *(const float4*)(src + row * FF + kc * 8 + 4);
        short8 v;
        v[0]=(short)f2bf(f0.x); v[1]=(short)f2bf(f0.y); v[2]=(short)f2bf(f0.z); v[3]=(short)f2bf(f0.w);
        v[4]=(short)f2bf(f1.x); v[5]=(short)f2bf(f1.y); v[6]=(short)f2bf(f1.z); v[7]=(short)f2bf(f1.w);
        int byte = row * 512 + kc * 16;
        byte ^= (row & 7) << 4;
        *(short8*)(As + byte) = v;
    }
    __syncthreads();

    const int nb = wid * 64;
    f32x4 acc[2][4];
#pragma unroll
    for (int m = 0; m < 2; ++m)
#pragma unroll
        for (int n = 0; n < 4; ++n) acc[m][n] = (f32x4){0.f, 0.f, 0.f, 0.f};

    for (int ks = 0; ks < 8; ++ks) {
        short8 a[2];
#pragma unroll
        for (int m = 0; m < 2; ++m) {
            const int row = m * 16 + (lane & 15);
            int byte = row * 512 + ks * 64 + (lane >> 4) * 16;
            byte ^= (row & 7) << 4;
            a[m] = *(const short8*)(As + byte);
        }
#pragma unroll
        for (int n = 0; n < 4; ++n) {
            const int col = nb + n * 16 + (lane & 15);
            const short8 b = *(const short8*)(WtG + col * 256 + ks * 32 + (lane >> 4) * 8);
#pragma unroll
            for (int m = 0; m < 2; ++m)
                acc[m][n] = __builtin_amdgcn_mfma_f32_16x16x32_bf16(a[m], b, acc[m][n], 0, 0, 0);
        }
    }
#pragma unroll
    for (int m = 0; m < 2; ++m)
#pragma unroll
        for (int n = 0; n < 4; ++n) {
            const int col = nb + n * 16 + (lane & 15);
#pragma unroll
            for (int r = 0; r < 4; ++r) {
                const int row = m * 16 + (lane >> 4) * 4 + r;
                sg[(size_t)(r0 + row) * UU + col] = f2bf(acc[m][n][r]);
            }
        }
}

// ---- sort pipeline: counting sort of edges by destination node, per type ----
__global__ __launch_bounds__(256) void k_hist(const int* __restrict__ eidx,
                                              int* __restrict__ cnt) {
    const int idx = blockIdx.x * 256 + threadIdx.x;   // 393216
    atomicAdd(&cnt[(idx >> 17) * M1 + eidx[idx]], 1);
}

__global__ __launch_bounds__(1024) void k_scan1(int* __restrict__ cnt,
                                                int* __restrict__ part) {
    const int t = blockIdx.x / SCAN_B, b = blockIdx.x % SCAN_B;
    const int i = b * 1024 + threadIdx.x;
    __shared__ int s[1024];
    const int v = (i < M1) ? cnt[t * M1 + i] : 0;
    s[threadIdx.x] = v;
    __syncthreads();
    for (int off = 1; off < 1024; off <<= 1) {
        const int x = (threadIdx.x >= off) ? s[threadIdx.x - off] : 0;
        __syncthreads();
        s[threadIdx.x] += x;
        __syncthreads();
    }
    if (i < M1) cnt[t * M1 + i] = s[threadIdx.x] - v;   // exclusive
    if (threadIdx.x == 1023) part[blockIdx.x] = s[1023];
}

__global__ void k_scan2(int* __restrict__ part) {
    const int t = threadIdx.x;
    if (t < TT) {
        int run = 0;
        for (int b = 0; b < SCAN_B; ++b) {
            const int p = part[t * SCAN_B + b];
            part[t * SCAN_B + b] = run;
            run += p;
        }
    }
}

__global__ __launch_bounds__(1024) void k_scan3(int* __restrict__ cnt,
                                                const int* __restrict__ part) {
    const int t = blockIdx.x / SCAN_B, b = blockIdx.x % SCAN_B;
    const int i = b * 1024 + threadIdx.x;
    if (i < M1) cnt[t * M1 + i] += part[blockIdx.x];
}

__global__ __launch_bounds__(256) void k_scatter(const int* __restrict__ eidx,
                                                 int* __restrict__ cur,
                                                 int* __restrict__ sorted,
                                                 int* __restrict__ snode) {
    const int idx = blockIdx.x * 256 + threadIdx.x;   // 393216
    const int t = idx >> 17;
    const int v = eidx[idx];
    const int slot = atomicAdd(&cur[t * M1 + v], 1);
    sorted[t * EE + slot] = idx & (EE - 1);
    snode[t * EE + slot]  = v;
}
// NOTE: after k_scatter, cnt[t*M1+v] == end offset of node v's segment;
// start(v) = (v==0) ? 0 : cnt[t*M1+v-1].

// ---- Phase A: edge GEMMs in SORTED order, msgs CSR-contiguous ----
// Single-barrier: all global loads issued up front (efeat gathered + sg via
// snode direct), both LDS tiles written, ONE __syncthreads, MFMA, epilogue.
// (256,4): VGPR+AGPR stays in the 128-reg bucket; round-7 showed (256,6)
// spills acc to scratch.
__global__ __launch_bounds__(256, 4) void k2_msgs(const float* __restrict__ efeat,
                                                  const short* __restrict__ WtGe,
                                                  const short* __restrict__ WtDe,
                                                  const float* __restrict__ bd,
                                                  const ushort* __restrict__ sg,
                                                  const int* __restrict__ sorted,
                                                  const int* __restrict__ snode,
                                                  ushort* __restrict__ msgs) {
    __shared__ char As[EPB * 256];        // 32 edges x 128 bf16, XOR-swizzled
    __shared__ ushort sgl[EPB][260];      // gathered sg rows (+4 pad)
    const int tid = threadIdx.x, lane = tid & 63, wid = tid >> 6;
    const int t = blockIdx.y;
    const int e0 = blockIdx.x * EPB;
    const int* sortedT = sorted + t * EE + e0;
    const int* snodeT  = snode + t * EE + e0;

    // --- issue efeat gathered loads (2 chunks of 8 floats per thread) ---
    float4 f0[2], f1[2];
    int rowj[2], kcj[2];
#pragma unroll
    for (int j = 0; j < 2; ++j) {
        const int chunk = j * 256 + tid;             // 512 chunks of 8 floats
        const int row = chunk >> 4, kc = chunk & 15;
        rowj[j] = row; kcj[j] = kc;
        const float* src = efeat + ((size_t)t * EE + sortedT[row]) * FED + kc * 8;
        f0[j] = *(const float4*)(src);
        f1[j] = *(const float4*)(src + 4);
    }

    // --- issue sg gathered loads (16 uints/thread); nodes direct via snode ---
    const int rbase = tid >> 7;       // 0/1: even/odd sgl rows
    const int c2 = tid & 127;         // uint column within a row
    uint gv[16];
#pragma unroll
    for (int j = 0; j < 16; ++j) {
        const int nd = snodeT[j * 2 + rbase];        // L1-broadcast across 128 thr
        gv[j] = *(const uint*)(sg + (size_t)nd * UU + c2 * 2);
    }

    // --- convert + write efeat tile to LDS (swizzled) ---
#pragma unroll
    for (int j = 0; j < 2; ++j) {
        short8 v;
        v[0]=(short)f2bf(f0[j].x); v[1]=(short)f2bf(f0[j].y); v[2]=(short)f2bf(f0[j].z); v[3]=(short)f2bf(f0[j].w);
        v[4]=(short)f2bf(f1[j].x); v[5]=(short)f2bf(f1[j].y); v[6]=(short)f2bf(f1[j].z); v[7]=(short)f2bf(f1[j].w);
        int byte = rowj[j] * 256 + kcj[j] * 16;
        byte ^= (rowj[j] & 7) << 4;
        *(short8*)(As + byte) = v;
    }
    // --- write gathered sg rows to LDS ---
#pragma unroll
    for (int j = 0; j < 16; ++j)
        *(uint*)&sgl[j * 2 + rbase][c2 * 2] = gv[j];

    __syncthreads();   // single barrier: As + sgl both ready

    const short* Bg = WtGe + t * 32768;  // [256n][128k]
    const short* Bd = WtDe + t * 32768;
    const int nb = wid * 64;

    f32x4 accg[2][4], accv[2][4];
#pragma unroll
    for (int m = 0; m < 2; ++m)
#pragma unroll
        for (int n = 0; n < 4; ++n) {
            accg[m][n] = (f32x4){0.f, 0.f, 0.f, 0.f};
            accv[m][n] = (f32x4){0.f, 0.f, 0.f, 0.f};
        }

#pragma unroll
    for (int ks = 0; ks < 4; ++ks) {
        short8 a[2];
#pragma unroll
        for (int m = 0; m < 2; ++m) {
            const int row = m * 16 + (lane & 15);
            int byte = row * 256 + ks * 64 + (lane >> 4) * 16;
            byte ^= (row & 7) << 4;
            a[m] = *(const short8*)(As + byte);
        }
#pragma unroll
        for (int n = 0; n < 4; ++n) {
            const int col = nb + n * 16 + (lane & 15);
            const int koff = ks * 32 + (lane >> 4) * 8;
            const short8 bg = *(const short8*)(Bg + col * 128 + koff);
            const short8 bv = *(const short8*)(Bd + col * 128 + koff);
#pragma unroll
            for (int m = 0; m < 2; ++m) {
                accg[m][n] = __builtin_amdgcn_mfma_f32_16x16x32_bf16(a[m], bg, accg[m][n], 0, 0, 0);
                accv[m][n] = __builtin_amdgcn_mfma_f32_16x16x32_bf16(a[m], bv, accv[m][n], 0, 0, 0);
            }
        }
    }
    // no second barrier: sgl was written before the single barrier

    float bias[4];
#pragma unroll
    for (int n = 0; n < 4; ++n) bias[n] = bd[t * UU + nb + n * 16 + (lane & 15)];

#pragma unroll
    for (int m = 0; m < 2; ++m) {
        const int ebase = m * 16 + (lane >> 4) * 4;
#pragma unroll
        for (int n = 0; n < 4; ++n) {
            const int col = nb + n * 16 + (lane & 15);
#pragma unroll
            for (int r = 0; r < 4; ++r) {
                const float sgv = bf2f(sgl[ebase + r][col]);
                const float e = __expf(-(sgv + accg[m][n][r]));
                const float g = __builtin_amdgcn_rcpf(1.f + e);   // fast sigmoid
                const float msg = (accv[m][n][r] + bias[n]) * g;
                msgs[((size_t)t * EE + e0 + ebase + r) * UU + col] = f2bf(msg);
            }
        }
    }
}

// ---- Phase B: per-node contiguous segment reduce, plain stores ----
__global__ __launch_bounds__(256, 8) void k3_reduce(const int* __restrict__ cnt,
                                                    const ushort* __restrict__ msgs,
                                                    float* __restrict__ out) {
    const int tid = threadIdx.x, lane = tid & 63, w = tid >> 6;
    const int v = blockIdx.x * 4 + w;   // node id, 4 waves/block; grid=25000
    float a0 = 0.f, a1 = 0.f, a2 = 0.f, a3 = 0.f;
#pragma unroll
    for (int t = 0; t < TT; ++t) {
        const int end   = cnt[t * M1 + v];
        const int start = (v == 0) ? 0 : cnt[t * M1 + v - 1];
        for (int e = start; e < end; ++e) {
            const uint2 d = *(const uint2*)(msgs + ((size_t)t * EE + e) * UU + lane * 4);
            a0 += bf2f((ushort)(d.x & 0xffff));
            a1 += bf2f((ushort)(d.x >> 16));
            a2 += bf2f((ushort)(d.y & 0xffff));
            a3 += bf2f((ushort)(d.y >> 16));
        }
    }
    float4 o; o.x = a0; o.y = a1; o.z = a2; o.w = a3;
    *(float4*)(out + (size_t)v * UU + lane * 4) = o;
}

// ---- Fallback (small ws): sorted + atomic kernel ----
__global__ __launch_bounds__(256, 4) void k2_edges(const int* __restrict__ eidx,
                                                   const float* __restrict__ efeat,
                                                   const short* __restrict__ WtGe,
                                                   const short* __restrict__ WtDe,
                                                   const float* __restrict__ bd,
                                                   const ushort* __restrict__ sg,
                                                   const int* __restrict__ sorted,
                                                   float* __restrict__ out) {
    __shared__ char As[EPB * 256];
    __shared__ ushort sgl[EPB][260];
    __shared__ int nds[EPB];
    const int tid = threadIdx.x, lane = tid & 63, wid = tid >> 6;
    const int t = blockIdx.y;
    const int e0 = blockIdx.x * EPB;
    const int* sortedT = sorted + t * EE + e0;
    const int* eidxT   = eidx + t * EE;

    if (tid < EPB) nds[tid] = eidxT[sortedT[tid]];
#pragma unroll
    for (int j = 0; j < 2; ++j) {
        const int chunk = j * 256 + tid;
        const int row = chunk >> 4, kc = chunk & 15;
        const int se = sortedT[row];
        const float* src = efeat + ((size_t)t * EE + se) * FED + kc * 8;
        const float4 f0 = *(const float4*)(src);
        const float4 f1 = *(const float4*)(src + 4);
        short8 v;
        v[0]=(short)f2bf(f0.x); v[1]=(short)f2bf(f0.y); v[2]=(short)f2bf(f0.z); v[3]=(short)f2bf(f0.w);
        v[4]=(short)f2bf(f1.x); v[5]=(short)f2bf(f1.y); v[6]=(short)f2bf(f1.z); v[7]=(short)f2bf(f1.w);
        int byte = row * 256 + kc * 16;
        byte ^= (row & 7) << 4;
        *(short8*)(As + byte) = v;
    }
    __syncthreads();
#pragma unroll
    for (int j = 0; j < 16; ++j) {
        const int item = j * 256 + tid;
        const int row = item >> 7, c2 = item & 127;
        const uint v = *(const uint*)(sg + (size_t)nds[row] * UU + c2 * 2);
        *(uint*)&sgl[row][c2 * 2] = v;
    }
    const short* Bg = WtGe + t * 32768;
    const short* Bd = WtDe + t * 32768;
    const int nb = wid * 64;
    f32x4 accg[2][4], accv[2][4];
#pragma unroll
    for (int m = 0; m < 2; ++m)
#pragma unroll
        for (int n = 0; n < 4; ++n) {
            accg[m][n] = (f32x4){0.f, 0.f, 0.f, 0.f};
            accv[m][n] = (f32x4){0.f, 0.f, 0.f, 0.f};
        }
#pragma unroll
    for (int ks = 0; ks < 4; ++ks) {
        short8 a[2];
#pragma unroll
        for (int m = 0; m < 2; ++m) {
            const int row = m * 16 + (lane & 15);
            int byte = row * 256 + ks * 64 + (lane >> 4) * 16;
            byte ^= (row & 7) << 4;
            a[m] = *(const short8*)(As + byte);
        }
#pragma unroll
        for (int n = 0; n < 4; ++n) {
            const int col = nb + n * 16 + (lane & 15);
            const int koff = ks * 32 + (lane >> 4) * 8;
            const short8 bg = *(const short8*)(Bg + col * 128 + koff);
            const short8 bv = *(const short8*)(Bd + col * 128 + koff);
#pragma unroll
            for (int m = 0; m < 2; ++m) {
                accg[m][n] = __builtin_amdgcn_mfma_f32_16x16x32_bf16(a[m], bg, accg[m][n], 0, 0, 0);
                accv[m][n] = __builtin_amdgcn_mfma_f32_16x16x32_bf16(a[m], bv, accv[m][n], 0, 0, 0);
            }
        }
    }
    __syncthreads();
    float bias[4];
#pragma unroll
    for (int n = 0; n < 4; ++n) bias[n] = bd[t * UU + nb + n * 16 + (lane & 15)];
#pragma unroll
    for (int m = 0; m < 2; ++m) {
        const int ebase = m * 16 + (lane >> 4) * 4;
        int node[4];
#pragma unroll
        for (int r = 0; r < 4; ++r) node[r] = nds[ebase + r];
#pragma unroll
        for (int n = 0; n < 4; ++n) {
            const int col = nb + n * 16 + (lane & 15);
            float carry = 0.f;
#pragma unroll
            for (int r = 0; r < 4; ++r) {
                const float sgv = bf2f(sgl[ebase + r][col]);
                const float e = __expf(-(sgv + accg[m][n][r]));
                const float g = __builtin_amdgcn_rcpf(1.f + e);
                carry += (accv[m][n][r] + bias[n]) * g;
                if (r == 3 || node[r + 1] != node[r]) {
                    atomicAdd(&out[(size_t)node[r] * UU + col], carry);
                    carry = 0.f;
                }
            }
        }
    }
}

extern "C" void kernel_launch(void* const* d_in, const int* in_sizes, int n_in,
                              void* d_out, int out_size, void* d_ws, size_t ws_size,
                              hipStream_t stream) {
    const float* feats = (const float*)d_in[0];
    const int*   eidx  = (const int*)d_in[1];
    const float* efeat = (const float*)d_in[2];
    const float* Wg    = (const float*)d_in[3];
    const float* Wge   = (const float*)d_in[4];
    const float* Wde   = (const float*)d_in[5];
    const float* bd    = (const float*)d_in[6];
    float* out = (float*)d_out;

    char* ws = (char*)d_ws;
    size_t off = 0;
    auto alloc = [&](size_t bytes) { char* p = ws + off; off = (off + bytes + 511) & ~(size_t)511; return p; };
    ushort* sg   = (ushort*)alloc((size_t)M1 * UU * 2);          // 51.2 MB
    short* WtG   = (short*)alloc(256 * 256 * 2);
    short* WtGe  = (short*)alloc((size_t)TT * FED * UU * 2);
    short* WtDe  = (short*)alloc((size_t)TT * FED * UU * 2);
    int* cnt     = (int*)alloc((size_t)TT * M1 * 4);             // 1.2 MB
    int* part    = (int*)alloc(4096);
    int* sorted  = (int*)alloc((size_t)TT * EE * 4);             // 1.57 MB
    int* snode   = (int*)alloc((size_t)TT * EE * 4);             // 1.57 MB
    const size_t small_needed = off;
    ushort* msgs = (ushort*)alloc((size_t)TT * EE * UU * 2);     // 201.3 MB
    const size_t big_needed = off;

    hipMemsetAsync(cnt, 0, (size_t)TT * M1 * 4, stream);
    k_prep<<<262144 / 256, 256, 0, stream>>>(Wg, Wge, Wde, WtG, WtGe, WtDe);
    k1_srcgate<<<M1 / 32, 256, 0, stream>>>(feats, WtG, sg);

    k_hist<<<(TT * EE) / 256, 256, 0, stream>>>(eidx, cnt);
    k_scan1<<<TT * SCAN_B, 1024, 0, stream>>>(cnt, part);
    k_scan2<<<1, 64, 0, stream>>>(part);
    k_scan3<<<TT * SCAN_B, 1024, 0, stream>>>(cnt, part);
    k_scatter<<<(TT * EE) / 256, 256, 0, stream>>>(eidx, cnt, sorted, snode);

    if (ws_size >= big_needed) {
        k2_msgs<<<dim3(EE / EPB, TT), 256, 0, stream>>>(efeat, WtGe, WtDe, bd,
                                                        (const ushort*)sg, sorted, snode, msgs);
        k3_reduce<<<M1 / 4, 256, 0, stream>>>(cnt, (const ushort*)msgs, out);
    } else if (ws_size >= small_needed) {
        hipMemsetAsync(d_out, 0, (size_t)out_size * sizeof(float), stream);
        k2_edges<<<dim3(EE / EPB, TT), 256, 0, stream>>>(eidx, efeat, WtGe, WtDe, bd,
                                                         (const ushort*)sg, sorted, out);
    }
}